// Round 13
// baseline (353.705 us; speedup 1.0000x reference)
//
#include <hip/hip_runtime.h>

typedef unsigned short u16;
typedef unsigned char u8;
typedef short s16x8 __attribute__((ext_vector_type(8)));
typedef unsigned short u16x4 __attribute__((ext_vector_type(4)));
typedef float f32x4 __attribute__((ext_vector_type(4)));
typedef int i32x4 __attribute__((ext_vector_type(4)));
typedef int i32x8 __attribute__((ext_vector_type(8)));

#define AS1 __attribute__((address_space(1)))
#define AS3 __attribute__((address_space(3)))

// async global->LDS, 16B per lane; LDS dest = wave-uniform base + lane*16
__device__ __forceinline__ void g2l16(const void* g, void* l) {
  __builtin_amdgcn_global_load_lds((const AS1 void*)g, (AS3 void*)l, 16, 0, 0);
}

__device__ __forceinline__ float b2f(u16 u) {
  union { unsigned int i; float f; } x; x.i = ((unsigned int)u) << 16; return x.f;
}
__device__ __forceinline__ u16 f2b(float f) {  // round-to-nearest-even
  unsigned int u = __builtin_bit_cast(unsigned int, f);
  return (u16)((u + 0x7fffu + ((u >> 16) & 1u)) >> 16);
}
__device__ __forceinline__ u8 f2e4m3(float v) {
  int p = __builtin_amdgcn_cvt_pk_fp8_f32(v, 0.f, 0, false);
  return (u8)(p & 0xff);
}
__device__ __forceinline__ float sigm(float x) { return 1.f / (1.f + __expf(-x)); }
__device__ __forceinline__ float tanh_f(float x) { return 2.f / (1.f + __expf(-2.f * x)) - 1.f; }

// dims: T=48 N=4096 F_IN=H1=F_OUT=64; TH = 3072

// ---------------- kpre: adj->fp8 + weight prep + k1 (XHT), one launch ----------------
// (r8 exact version: linear adj8 layout)
__global__ __launch_bounds__(256) void kpre(
    const float* __restrict__ a, u8* __restrict__ ab,
    const float* __restrict__ fcw, const float* __restrict__ fcb,
    const float* __restrict__ x, u8* __restrict__ xht,
    const float* __restrict__ Wz, const float* __restrict__ Wr, const float* __restrict__ Wh,
    const float* __restrict__ Lz, const float* __restrict__ Lr, const float* __restrict__ Lh,
    u16* __restrict__ wct, u16* __restrict__ lbt) {
  int b = blockIdx.x, tid = threadIdx.x;
  if (b < 4096) {
    size_t idx = (size_t)b * 256 + tid;   // lane-contiguous float4 index
    const float4* src = (const float4*)a;
    unsigned int* dst = (unsigned int*)ab;
#pragma unroll
    for (int k = 0; k < 4; ++k) {
      float4 v = src[idx + (size_t)k * 1048576];
      unsigned int p = __builtin_amdgcn_cvt_pk_fp8_f32(v.x * 4096.f, v.y * 4096.f, 0, false);
      p = __builtin_amdgcn_cvt_pk_fp8_f32(v.z * 4096.f, v.w * 4096.f, p, true);
      dst[idx + (size_t)k * 1048576] = p;
    }
    return;
  }
  if (b < 4144) {
    int idx = (b - 4096) * 256 + tid;  // 0..12287
    int c_cat = idx >> 6, hh = idx & 63;
    int g = c_cat >> 6, c = c_cat & 63;
    const float* W = (g == 0) ? Wz : (g == 1) ? Wr : Wh;
    const float* L = (g == 0) ? Lz : (g == 1) ? Lr : Lh;
    float acc = 0.f;
    for (int m = 0; m < 64; ++m) acc += W[hh * 64 + m] * L[m * 64 + c];
    wct[c_cat * 64 + hh] = f2b(acc);
    return;
  }
  if (b < 4147) {
    int g = b - 4144;
    const float* L = (g == 0) ? Lz : (g == 1) ? Lr : Lh;
    for (int i = 0; i < 16; ++i) {
      int idx = tid * 16 + i; int c = idx >> 6, hh = idx & 63;
      lbt[g * 4096 + c * 64 + hh] = f2b(L[(64 + hh) * 64 + c]);
    }
    return;
  }
  // ---- XHT part: kb in [0,1536): t = kb>>5, n0 = (kb&31)*128 ----
  int kb = b - 4147;
  int t = kb >> 5, n0 = (kb & 31) * 128;
  __shared__ __align__(16) u16 xs[128 * 72];   // padded: 2-way banks
  __shared__ __align__(16) u16 fw[64 * 72];
  __shared__ __align__(16) u8 xh8[64 * 128];   // [h][node]
  __shared__ float fb[64];
  int w = tid >> 6, l = tid & 63;
#pragma unroll
  for (int i = 0; i < 16; ++i) {       // fw[h][f] = fc_w[f][h], coalesced fp32 reads
    int idx = tid + i * 256;
    int h = idx & 63, f = idx >> 6;
    fw[h * 72 + f] = f2b(fcw[f * 64 + h]);
  }
  const float4* xg = (const float4*)(x + ((size_t)t * 4096 + n0) * 64);
#pragma unroll
  for (int i = 0; i < 8; ++i) {
    int f = tid + i * 256;             // lane-contiguous float4 index
    float4 v = xg[f];
    u16x4 p; p[0] = f2b(v.x); p[1] = f2b(v.y); p[2] = f2b(v.z); p[3] = f2b(v.w);
    *(u16x4*)&xs[(f >> 4) * 72 + (f & 15) * 4] = p;
  }
  if (tid < 64) fb[tid] = fcb[tid];
  __syncthreads();

  int lm = l & 15, q = l >> 4;
  f32x4 acc[4][2];
#pragma unroll
  for (int i = 0; i < 4; ++i)
#pragma unroll
    for (int j = 0; j < 2; ++j)
#pragma unroll
      for (int r = 0; r < 4; ++r) acc[i][j][r] = 0.f;
#pragma unroll
  for (int s = 0; s < 2; ++s) {
    s16x8 af[4], bf[2];
#pragma unroll
    for (int i = 0; i < 4; ++i) af[i] = *(const s16x8*)&fw[(16 * i + lm) * 72 + 32 * s + q * 8];
#pragma unroll
    for (int j = 0; j < 2; ++j) bf[j] = *(const s16x8*)&xs[(32 * w + 16 * j + lm) * 72 + 32 * s + q * 8];
#pragma unroll
    for (int i = 0; i < 4; ++i)
#pragma unroll
      for (int j = 0; j < 2; ++j)
        acc[i][j] = __builtin_amdgcn_mfma_f32_16x16x32_bf16(af[i], bf[j], acc[i][j], 0, 0, 0);
  }
#pragma unroll
  for (int i = 0; i < 4; ++i)
#pragma unroll
    for (int j = 0; j < 2; ++j) {
      int node = 32 * w + 16 * j + lm;
      int h0 = 16 * i + q * 4;
#pragma unroll
      for (int r = 0; r < 4; ++r) {
        float v = acc[i][j][r] + fb[h0 + r];
        xh8[(h0 + r) * 128 + node] = f2e4m3(v > 0.f ? v : 0.f);
      }
    }
  __syncthreads();
  {
    int h = tid >> 2, seg = tid & 3;   // 32 bytes per thread
    u8* dst = xht + (size_t)(t * 64 + h) * 4096 + n0 + seg * 32;
    const u8* src = &xh8[h * 128 + seg * 32];
    *(i32x4*)dst = *(const i32x4*)src;
    *(i32x4*)(dst + 16) = *(const i32x4*)(src + 16);
  }
}

// ---------------- k2: M = adj8 @ XH8, MX fp8 K=128, 128x192 tile ----------------
// (r8 exact version: both operands g2l16-staged, double-buffered 2x40KB,
// one __syncthreads per K-step, grid (16,32) = 2 blocks/CU)
__global__ __launch_bounds__(256) void k2(
    const u8* __restrict__ A, const u8* __restrict__ B, u16* __restrict__ M) {
  __shared__ __align__(16) u8 sh[81920];   // 2 x (A 16KB + B 24KB)
  int tid = threadIdx.x, w = tid >> 6, l = tid & 63;
  int nt = blockIdx.x, mt = blockIdx.y;
  const u8* Ab = A + (size_t)mt * 128 * 4096;
  const u8* Bb = B + (size_t)nt * 192 * 4096;
  int lm = l & 15, q = l >> 4;
  int wm = w >> 1, wn = w & 1;
  int srow = l >> 3, scol = l & 7;
  f32x4 acc[4][6];
#pragma unroll
  for (int i = 0; i < 4; ++i)
#pragma unroll
    for (int j = 0; j < 6; ++j)
#pragma unroll
      for (int r = 0; r < 4; ++r) acc[i][j][r] = 0.f;

#define STAGE(bsel, kk)                                                       \
  do {                                                                        \
    u8* As_ = sh + (bsel) * 40960;                                            \
    u8* Bs_ = As_ + 16384;                                                    \
    _Pragma("unroll") for (int j = 0; j < 4; ++j) {   /* A: 32 rows/wave */   \
      int r0 = 32 * w + 8 * j;                                                \
      int row = r0 + srow;                                                    \
      int c = (scol - row) & 7;                                               \
      g2l16(Ab + (size_t)row * 4096 + (kk) + c * 16, As_ + r0 * 128);         \
    }                                                                         \
    _Pragma("unroll") for (int j = 0; j < 6; ++j) {   /* B: 48 rows/wave */   \
      int r0 = 48 * w + 8 * j;                                                \
      int row = r0 + srow;                                                    \
      int c = (scol - row) & 7;                                               \
      g2l16(Bb + (size_t)row * 4096 + (kk) + c * 16, Bs_ + r0 * 128);         \
    }                                                                         \
  } while (0)

  STAGE(0, 0);
  __syncthreads();                     // buf0 ready

  for (int it = 0; it < 32; ++it) {
    int k0b = it * 128;
    int cur = it & 1;
    if (it < 31) STAGE(cur ^ 1, k0b + 128);   // prefetch next K-tile into other buffer
    const u8* As = sh + cur * 40960;
    const u8* Bs = As + 16384;
    i32x8 a8[4];
#pragma unroll
    for (int i = 0; i < 4; ++i) {
      int ra = 64 * wm + 16 * i + lm;
      int p0 = (2 * q + ra) & 7, p1 = (2 * q + 1 + ra) & 7;
      i32x4 lo = *(const i32x4*)&As[ra * 128 + p0 * 16];
      i32x4 hi = *(const i32x4*)&As[ra * 128 + p1 * 16];
      a8[i] = __builtin_shufflevector(lo, hi, 0, 1, 2, 3, 4, 5, 6, 7);
    }
#pragma unroll
    for (int j = 0; j < 6; ++j) {
      int rb = 96 * wn + 16 * j + lm;
      int q0 = (2 * q + rb) & 7, q1 = (2 * q + 1 + rb) & 7;
      i32x4 lo2 = *(const i32x4*)&Bs[rb * 128 + q0 * 16];
      i32x4 hi2 = *(const i32x4*)&Bs[rb * 128 + q1 * 16];
      i32x8 b8 = __builtin_shufflevector(lo2, hi2, 0, 1, 2, 3, 4, 5, 6, 7);
#pragma unroll
      for (int i = 0; i < 4; ++i)
        acc[i][j] = __builtin_amdgcn_mfma_scale_f32_16x16x128_f8f6f4(
            a8[i], b8, acc[i][j], 0, 0, 0, 127, 0, 127);  // fmt=fp8, scale=2^0
    }
    __syncthreads();   // one barrier/iter: drains next-buf writes AND cur-buf reads
  }
#undef STAGE

  // epilogue: 2-pass transpose through LDS. tb = [64][200] u16 (25.6KB)
  u16* tb = (u16*)sh;
  const float sc = 1.f / 4096.f;
#pragma unroll
  for (int p = 0; p < 2; ++p) {
    if (p) __syncthreads();            // pass-0 LDS reads done before overwrite
    if (wm == p) {
#pragma unroll
      for (int i = 0; i < 4; ++i)
#pragma unroll
        for (int j = 0; j < 6; ++j)
#pragma unroll
          for (int r = 0; r < 4; ++r)
            tb[(16 * i + 4 * q + r) * 200 + 96 * wn + 16 * j + lm] = f2b(acc[i][j][r] * sc);
    }
    __syncthreads();
    int row = tid >> 2, seg = tid & 3;   // 64 rows x 384B; 96B (48 u16) per thread
    u16* dst = M + (size_t)(mt * 128 + p * 64 + row) * 3072 + nt * 192 + seg * 48;
    const u16* src = &tb[row * 200 + seg * 48];
#pragma unroll
    for (int v = 0; v < 6; ++v)
      *(i32x4*)(dst + 8 * v) = *(const i32x4*)(src + 8 * v);
  }
}

// ---------------- k3: BARRIER-FREE GRU scan -- one WAVE owns 16 nodes ----------------
// r8's k3 ran 48 steps x 2 __syncthreads at 1 block/CU: ~2900 cy/step vs
// ~200 cy of issue = 93% stall. Here each wave computes ALL 64 output
// features of its 16 nodes (4 x 16-feat MFMA tiles: the f-loop replaces the
// wave dimension; operand patterns and accumulation order identical ->
// bit-identical output). h never crosses waves, so the cross-feature mix
// routes through WAVE-PRIVATE LDS (per-wave DS ops are in-order): ZERO
// barriers in the scan. 256 blocks x 64 threads = 256 free-running waves.
// afl (critical-path L weights) in registers (96 VGPR); afw (M-part,
// off-critical) staged in LDS pitch-72 to cap pressure (~330 VGPR total,
// under the 450-no-spill threshold; 1 wave/SIMD is fine -- latency-bound).
__global__ __launch_bounds__(64, 1) void k3(
    const u16* __restrict__ M, const u16* __restrict__ wct, const u16* __restrict__ lbt,
    const float* __restrict__ bz, const float* __restrict__ br, const float* __restrict__ bh,
    float* __restrict__ out) {
  __shared__ __align__(16) u16 wlds[192 * 72];        // wct staged (27.6KB)
  __shared__ __align__(16) u16 hhi[16 * 72], hlo[16 * 72];
  __shared__ __align__(16) u16 rhi[16 * 72], rlo[16 * 72];
  int l = threadIdx.x & 63;
  int nw0 = blockIdx.x * 16;
  int lm = l & 15, q = l >> 4;

  // stage wct -> LDS (pitch 64 -> 72; coalesced 16B reads)
  for (int idx = l; idx < 1536; idx += 64) {          // 192 rows x 8 chunks
    int row = idx >> 3, cs = idx & 7;
    *(s16x8*)&wlds[row * 72 + cs * 8] = *(const s16x8*)&wct[row * 64 + cs * 8];
  }
  for (int i = l; i < 1152; i += 64) { hhi[i] = 0; hlo[i] = 0; }

  s16x8 afl[3][4][2];
#pragma unroll
  for (int g = 0; g < 3; ++g)
#pragma unroll
    for (int f = 0; f < 4; ++f)
#pragma unroll
      for (int s = 0; s < 2; ++s)
        afl[g][f][s] = *(const s16x8*)&lbt[g * 4096 + (16 * f + lm) * 64 + 32 * s + 8 * q];

  f32x4 bzv[4], brv[4], bhv[4], hv[4];
#pragma unroll
  for (int f = 0; f < 4; ++f)
#pragma unroll
    for (int r = 0; r < 4; ++r) {
      bzv[f][r] = bz[16 * f + 4 * q + r];
      brv[f][r] = br[16 * f + 4 * q + r];
      bhv[f][r] = bh[16 * f + 4 * q + r];
      hv[f][r] = 0.f;
    }
  const f32x4 zf = {0.f, 0.f, 0.f, 0.f};

  const u16* Mrow = M + (size_t)(nw0 + lm) * 3072;
  s16x8 Mn[2];
  Mn[0] = *(const s16x8*)&Mrow[8 * q];
  Mn[1] = *(const s16x8*)&Mrow[32 + 8 * q];

  // M-part + bias for a step (afw frags read from wave-private LDS)
#define MPART(uC, g, bias)                                                    \
  _Pragma("unroll") for (int f = 0; f < 4; ++f) {                             \
    s16x8 w0 = *(const s16x8*)&wlds[((g) * 64 + 16 * f + lm) * 72 + 8 * q];   \
    s16x8 w1 = *(const s16x8*)&wlds[((g) * 64 + 16 * f + lm) * 72 + 32 + 8 * q]; \
    uC[f] = __builtin_amdgcn_mfma_f32_16x16x32_bf16(w0, Mn[0], bias[f], 0, 0, 0); \
    uC[f] = __builtin_amdgcn_mfma_f32_16x16x32_bf16(w1, Mn[1], uC[f], 0, 0, 0); \
  }

  f32x4 uzwC[4], urwC[4], uhwC[4];
  MPART(uzwC, 0, bzv)
  MPART(urwC, 1, brv)
  MPART(uhwC, 2, bhv)

  for (int t = 0; t < 48; ++t) {
    if (t < 47) {                      // prefetch M column-block t+1 (used at step end)
      Mn[0] = *(const s16x8*)&Mrow[(t + 1) * 64 + 8 * q];
      Mn[1] = *(const s16x8*)&Mrow[(t + 1) * 64 + 32 + 8 * q];
    }
    // ---- z, r gates ----
    s16x8 hh0 = *(const s16x8*)&hhi[lm * 72 + 8 * q];
    s16x8 hh1 = *(const s16x8*)&hhi[lm * 72 + 32 + 8 * q];
    s16x8 hl0 = *(const s16x8*)&hlo[lm * 72 + 8 * q];
    s16x8 hl1 = *(const s16x8*)&hlo[lm * 72 + 32 + 8 * q];
    f32x4 zA[4], zB[4], rA[4], rB[4];
#pragma unroll
    for (int f = 0; f < 4; ++f) {
      zA[f] = __builtin_amdgcn_mfma_f32_16x16x32_bf16(afl[0][f][0], hh0, uzwC[f], 0, 0, 0);
      zA[f] = __builtin_amdgcn_mfma_f32_16x16x32_bf16(afl[0][f][1], hh1, zA[f], 0, 0, 0);
      zB[f] = __builtin_amdgcn_mfma_f32_16x16x32_bf16(afl[0][f][0], hl0, zf, 0, 0, 0);
      zB[f] = __builtin_amdgcn_mfma_f32_16x16x32_bf16(afl[0][f][1], hl1, zB[f], 0, 0, 0);
      rA[f] = __builtin_amdgcn_mfma_f32_16x16x32_bf16(afl[1][f][0], hh0, urwC[f], 0, 0, 0);
      rA[f] = __builtin_amdgcn_mfma_f32_16x16x32_bf16(afl[1][f][1], hh1, rA[f], 0, 0, 0);
      rB[f] = __builtin_amdgcn_mfma_f32_16x16x32_bf16(afl[1][f][0], hl0, zf, 0, 0, 0);
      rB[f] = __builtin_amdgcn_mfma_f32_16x16x32_bf16(afl[1][f][1], hl1, rB[f], 0, 0, 0);
    }
    f32x4 zv[4], rv[4];
#pragma unroll
    for (int f = 0; f < 4; ++f)
#pragma unroll
      for (int r = 0; r < 4; ++r) {
        zv[f][r] = sigm(zA[f][r] + zB[f][r]);
        rv[f][r] = sigm(rA[f][r] + rB[f][r]);
      }
    // h*r -> wave-private LDS (hi/lo); in-order DS makes the read-back safe
#pragma unroll
    for (int f = 0; f < 4; ++f) {
      u16x4 phi, plo;
#pragma unroll
      for (int r = 0; r < 4; ++r) {
        float p = hv[f][r] * rv[f][r];
        u16 hi = f2b(p); phi[r] = hi; plo[r] = f2b(p - b2f(hi));
      }
      *(u16x4*)&rhi[lm * 72 + 16 * f + 4 * q] = phi;
      *(u16x4*)&rlo[lm * 72 + 16 * f + 4 * q] = plo;
    }
    s16x8 rh0 = *(const s16x8*)&rhi[lm * 72 + 8 * q];
    s16x8 rh1 = *(const s16x8*)&rhi[lm * 72 + 32 + 8 * q];
    s16x8 rl0 = *(const s16x8*)&rlo[lm * 72 + 8 * q];
    s16x8 rl1 = *(const s16x8*)&rlo[lm * 72 + 32 + 8 * q];
    // ---- candidate + state update ----
    f32x4 hA[4], hB[4];
#pragma unroll
    for (int f = 0; f < 4; ++f) {
      hA[f] = __builtin_amdgcn_mfma_f32_16x16x32_bf16(afl[2][f][0], rh0, uhwC[f], 0, 0, 0);
      hA[f] = __builtin_amdgcn_mfma_f32_16x16x32_bf16(afl[2][f][1], rh1, hA[f], 0, 0, 0);
      hB[f] = __builtin_amdgcn_mfma_f32_16x16x32_bf16(afl[2][f][0], rl0, zf, 0, 0, 0);
      hB[f] = __builtin_amdgcn_mfma_f32_16x16x32_bf16(afl[2][f][1], rl1, hB[f], 0, 0, 0);
    }
#pragma unroll
    for (int f = 0; f < 4; ++f) {
      u16x4 phi, plo;
#pragma unroll
      for (int r = 0; r < 4; ++r) {
        float th = tanh_f(hA[f][r] + hB[f][r]);
        float hn = zv[f][r] * hv[f][r] + (1.f - zv[f][r]) * th;
        hv[f][r] = hn;
        u16 hi = f2b(hn); phi[r] = hi; plo[r] = f2b(hn - b2f(hi));
      }
      *(u16x4*)&hhi[lm * 72 + 16 * f + 4 * q] = phi;
      *(u16x4*)&hlo[lm * 72 + 16 * f + 4 * q] = plo;
    }
    if (t < 47) {                      // next step's M-part (off critical path)
      MPART(uzwC, 0, bzv)
      MPART(urwC, 1, brv)
      MPART(uhwC, 2, bhv)
    }
  }
#undef MPART
#pragma unroll
  for (int f = 0; f < 4; ++f)
#pragma unroll
    for (int r = 0; r < 4; ++r)
      out[(size_t)(nw0 + lm) * 64 + 16 * f + 4 * q + r] = hv[f][r];
}

extern "C" void kernel_launch(void* const* d_in, const int* in_sizes, int n_in,
                              void* d_out, int out_size, void* d_ws, size_t ws_size,
                              hipStream_t stream) {
  const float* x   = (const float*)d_in[0];
  const float* adj = (const float*)d_in[1];
  const float* fcw = (const float*)d_in[2];
  const float* fcb = (const float*)d_in[3];
  const float* Wz  = (const float*)d_in[4];
  const float* Wr  = (const float*)d_in[5];
  const float* Wh  = (const float*)d_in[6];
  const float* Lz  = (const float*)d_in[7];
  const float* Lr  = (const float*)d_in[8];
  const float* Lh  = (const float*)d_in[9];
  const float* bz  = (const float*)d_in[10];
  const float* br  = (const float*)d_in[11];
  const float* bh  = (const float*)d_in[12];
  char* ws = (char*)d_ws;
  // ws layout (bytes):
  u8*  xht  = (u8*)(ws);                           // [3072][4096] fp8: 12,582,912
  u8*  adj8 = (u8*)(ws + (size_t)12582912);        // [4096][4096] fp8: 16,777,216
  u16* Mm   = (u16*)(ws + (size_t)29360128);       // [4096][3072] bf16: 25,165,824
  u16* wct  = (u16*)(ws + (size_t)54525952);       // 24 KB
  u16* lbt  = (u16*)(ws + (size_t)54550528);       // 24 KB
  float* outp = (float*)d_out;

  hipLaunchKernelGGL(kpre, dim3(5683), dim3(256), 0, stream,
                     adj, adj8, fcw, fcb, x, xht, Wz, Wr, Wh, Lz, Lr, Lh, wct, lbt);
  hipLaunchKernelGGL(k2, dim3(16, 32), dim3(256), 0, stream, adj8, xht, Mm);
  hipLaunchKernelGGL(k3, dim3(256), dim3(64), 0, stream, Mm, wct, lbt, bz, br, bh, outp);
}